// Round 3
// baseline (125728.918 us; speedup 1.0000x reference)
//
#include <hip/hip_runtime.h>
#include <math.h>

#define Bsz 64
#define Tsz 1024
#define Isz 128
#define Hsz 512
#define KH  256   // H/2
#define Osz 10

// ---------------------------------------------------------------------------
// Register-tiled fp32 GEMM: C[M,N] = A[M,K] @ Bw[K,N] + bias[N]
// ---------------------------------------------------------------------------
__global__ __launch_bounds__(256) void gemm_bias_kernel(
    const float* __restrict__ A, const float* __restrict__ Bw,
    const float* __restrict__ bias, float* __restrict__ C,
    int M, int N, int K)
{
  __shared__ float As[32][65];
  const int tid = threadIdx.x;
  const int m0 = blockIdx.x * 64;
  const int n0 = blockIdx.y * 64;
  const int ty = tid >> 4, tx = tid & 15;

  float acc[4][4] = {{0.f}};

  for (int kk = 0; kk < K; kk += 32) {
    __syncthreads();
#pragma unroll
    for (int i = tid; i < 64 * 32; i += 256) {
      int m = i >> 5, k = i & 31;
      As[k][m] = A[(size_t)(m0 + m) * K + kk + k];
    }
    __syncthreads();
#pragma unroll
    for (int k = 0; k < 32; ++k) {
      float a0 = As[k][ty * 4 + 0];
      float a1 = As[k][ty * 4 + 1];
      float a2 = As[k][ty * 4 + 2];
      float a3 = As[k][ty * 4 + 3];
      const float4 bv = *(const float4*)(&Bw[(size_t)(kk + k) * N + n0 + tx * 4]);
      acc[0][0] += a0 * bv.x; acc[0][1] += a0 * bv.y; acc[0][2] += a0 * bv.z; acc[0][3] += a0 * bv.w;
      acc[1][0] += a1 * bv.x; acc[1][1] += a1 * bv.y; acc[1][2] += a1 * bv.z; acc[1][3] += a1 * bv.w;
      acc[2][0] += a2 * bv.x; acc[2][1] += a2 * bv.y; acc[2][2] += a2 * bv.z; acc[2][3] += a2 * bv.w;
      acc[3][0] += a3 * bv.x; acc[3][1] += a3 * bv.y; acc[3][2] += a3 * bv.z; acc[3][3] += a3 * bv.w;
    }
  }

  const float4 bb = *(const float4*)(&bias[n0 + tx * 4]);
#pragma unroll
  for (int i = 0; i < 4; ++i) {
    float4 v;
    v.x = acc[i][0] + bb.x; v.y = acc[i][1] + bb.y;
    v.z = acc[i][2] + bb.z; v.w = acc[i][3] + bb.w;
    *(float4*)(&C[(size_t)(m0 + ty * 4 + i) * N + n0 + tx * 4]) = v;
  }
}

// ---------------------------------------------------------------------------
// bf16 (RNE) pack helpers.
// low 16 = even-index element (pairs with .x), high 16 = odd-index element.
// ---------------------------------------------------------------------------
__device__ __forceinline__ unsigned bf16rne(float f) {
  unsigned u = __float_as_uint(f);
  return (u + 0x7fffu + ((u >> 16) & 1u)) >> 16;
}
__device__ __forceinline__ float lo16(unsigned u) { return __uint_as_float(u << 16); }
__device__ __forceinline__ float hi16(unsigned u) { return __uint_as_float(u & 0xffff0000u); }

// in [R][C] f32 -> out [R/2][C] u32, pairing consecutive rows.
__global__ __launch_bounds__(256) void pack_rows_kernel(
    const float* __restrict__ in, unsigned* __restrict__ out, int R2, int C)
{
  int i = blockIdx.x * 256 + threadIdx.x;
  if (i >= R2 * C) return;
  int r2 = i / C, c = i - r2 * C;
  unsigned lo = bf16rne(in[(size_t)(2 * r2) * C + c]);
  unsigned hi = bf16rne(in[(size_t)(2 * r2 + 1) * C + c]);
  out[i] = lo | (hi << 16);
}

// W_rec [512][512] -> P0[i2][j] = pack(W_rec[j][2*i2], W_rec[j][2*i2+1])
__global__ __launch_bounds__(256) void pack_wrecT_kernel(
    const float* __restrict__ W_rec, unsigned* __restrict__ P0)
{
  int i = blockIdx.x * 256 + threadIdx.x;
  if (i >= 256 * Hsz) return;
  int i2 = i >> 9, j = i & 511;
  unsigned lo = bf16rne(W_rec[(size_t)j * Hsz + 2 * i2]);
  unsigned hi = bf16rne(W_rec[(size_t)j * Hsz + 2 * i2 + 1]);
  P0[i] = lo | (hi << 16);
}

// ---------------------------------------------------------------------------
// Scan: 256 WGs = 4 per batch element (g&63 = b, g>>6 = q; group members are
// {b, b+64, b+128, b+192} -> same XCD under round-robin dispatch, perf only).
// WG q owns drive/tau2 cols [128q,128q+128) and tau1 cols [64q,64q+64).
// Weight slices live in VGPRs (128 packed u32/thread), loaded once.
// Per step: 2 device-scope group barriers; barrier1 wait hidden behind the
// drive matvec. h/A exchanged via L2 (hstate/Astate in ws).
// ---------------------------------------------------------------------------
__global__ __launch_bounds__(512, 2) void scan_kernel(
    float* __restrict__ xps,           // in: xp [B,T,H]; out: hs [B,T,H]
    const float* __restrict__ U,       // [B,T,KH] (b_tau1 already added)
    const unsigned* __restrict__ P0,   // [256][512] packed W_rec^T pairs
    const unsigned* __restrict__ P1,   // [256][256] packed W_tau1[512:] row-pairs
    const unsigned* __restrict__ P2,   // [128][512] packed W_tau2 row-pairs
    const float* __restrict__ bias,    // [H]
    const float* __restrict__ b_tau2,  // [H]
    float* __restrict__ hstate,        // [B][H]   (zeroed)
    float* __restrict__ Astate,        // [B][KH]
    unsigned* __restrict__ ctrs)       // [B][64]  (zeroed, monotonic)
{
  const int g = blockIdx.x;
  const int b = g & 63;
  const int q = g >> 6;
  const int tid = threadIdx.x;
  const int kseg4 = tid >> 7, j128 = tid & 127;
  const int kseg8 = tid >> 6, c64  = tid & 63;

  __shared__ __align__(16) float hloc[Hsz];
  __shared__ __align__(16) float Aloc[KH];
  __shared__ float part_d[128][5];
  __shared__ float part_t1[64][9];
  __shared__ float part_t2[128][5];

  // --- one-time: weight slices into registers ---
  unsigned wd[64], w1[32], w2[32];
  {
    const unsigned* p0 = P0 + (size_t)(kseg4 * 64) * Hsz + q * 128 + j128;
#pragma unroll
    for (int i = 0; i < 64; ++i) wd[i] = p0[(size_t)i * Hsz];
    const unsigned* p1 = P1 + (size_t)(kseg8 * 32) * KH + q * 64 + c64;
#pragma unroll
    for (int i = 0; i < 32; ++i) w1[i] = p1[(size_t)i * KH];
    const unsigned* p2 = P2 + (size_t)(kseg4 * 32) * Hsz + q * 128 + j128;
#pragma unroll
    for (int i = 0; i < 32; ++i) w2[i] = p2[(size_t)i * Hsz];
  }

  float* __restrict__ hstate_b = hstate + (size_t)b * Hsz;
  float* __restrict__ Astate_b = Astate + (size_t)b * KH;
  unsigned* ctr = ctrs + (size_t)b * 64;   // 256B-strided counter

  const int col = q * 128 + j128;          // epilogue col (tid<128 active)
  const float bias_r = bias[col];
  const float bt2_r  = b_tau2[col];

  float* xprow = xps + (size_t)b * Tsz * Hsz;
  const float* Urow = U + (size_t)b * Tsz * KH;

  for (int t = 0; t < Tsz; ++t) {
    // --- stage h_{t-1} (fresh: L1 invalidated by the fence after barrier2) ---
    hloc[tid] = hstate_b[tid];
    const float xpv = (tid < 128) ? xprow[col] : 0.f;
    const float Uv  = (tid < 64)  ? Urow[q * 64 + tid] : 0.f;
    __syncthreads();

    // --- tau1 partial (its 64 cols, k-split by 8) ---
    {
      float p0a = 0.f, p1a = 0.f;
      const float4* h4 = (const float4*)&hloc[kseg8 * 64];
#pragma unroll
      for (int i = 0; i < 16; ++i) {
        const float4 hv = h4[i];
        const unsigned wa = w1[2 * i], wb = w1[2 * i + 1];
        p0a = fmaf(hv.x, lo16(wa), p0a); p1a = fmaf(hv.y, hi16(wa), p1a);
        p0a = fmaf(hv.z, lo16(wb), p0a); p1a = fmaf(hv.w, hi16(wb), p1a);
      }
      part_t1[c64][kseg8] = p0a + p1a;
    }
    __syncthreads();
    if (tid < 64) {
      float a = Uv;
#pragma unroll
      for (int s = 0; s < 8; ++s) a += part_t1[tid][s];
      Astate_b[q * 64 + tid] = fmaxf(a, 0.f);
    }
    __threadfence();
    __syncthreads();
    if (tid == 0) atomicAdd(ctr, 1u);      // signal barrier1 (A slice published)

    // --- drive partial (overlaps other WGs' phase A / barrier latency) ---
    {
      float d0 = 0.f, d1 = 0.f;
      const float4* h4 = (const float4*)&hloc[kseg4 * 128];
#pragma unroll
      for (int i = 0; i < 32; ++i) {
        const float4 hv = h4[i];
        const unsigned wa = wd[2 * i], wb = wd[2 * i + 1];
        d0 = fmaf(hv.x, lo16(wa), d0); d1 = fmaf(hv.y, hi16(wa), d1);
        d0 = fmaf(hv.z, lo16(wb), d0); d1 = fmaf(hv.w, hi16(wb), d1);
      }
      part_d[j128][kseg4] = d0 + d1;
    }

    // --- wait barrier1 ---
    if (tid == 0) {
      const unsigned tgt = 8u * (unsigned)t + 4u;
      while (__hip_atomic_load(ctr, __ATOMIC_RELAXED, __HIP_MEMORY_SCOPE_AGENT) < tgt)
        __builtin_amdgcn_s_sleep(1);
    }
    __syncthreads();
    __threadfence();                       // acquire: invalidate L1

    if (tid < KH) Aloc[tid] = Astate_b[tid];
    __syncthreads();

    // --- tau2 partial (its 128 cols, k-split by 4) ---
    {
      float s0 = 0.f, s1 = 0.f;
      const float4* a4 = (const float4*)&Aloc[kseg4 * 64];
#pragma unroll
      for (int i = 0; i < 16; ++i) {
        const float4 av = a4[i];
        const unsigned wa = w2[2 * i], wb = w2[2 * i + 1];
        s0 = fmaf(av.x, lo16(wa), s0); s1 = fmaf(av.y, hi16(wa), s1);
        s0 = fmaf(av.z, lo16(wb), s0); s1 = fmaf(av.w, hi16(wb), s1);
      }
      part_t2[j128][kseg4] = s0 + s1;
    }
    __syncthreads();

    // --- epilogue: tau, drive, Euler update, publish h slice ---
    if (tid < 128) {
      float s = bt2_r, d = xpv + bias_r;
#pragma unroll
      for (int sg = 0; sg < 4; ++sg) { s += part_t2[tid][sg]; d += part_d[tid][sg]; }
      const float tau = 5.0f + 45.0f / (1.0f + __expf(-s));
      const float drv = tanhf(d);
      const float hold = hloc[col];
      const float hnew = hold + (drv - hold) / tau;
      hstate_b[col] = hnew;
      xprow[col] = hnew;                   // hs output (dead xp slot)
    }
    __threadfence();
    __syncthreads();
    if (tid == 0) {
      atomicAdd(ctr, 1u);                  // signal barrier2
      const unsigned tgt = 8u * (unsigned)t + 8u;
      while (__hip_atomic_load(ctr, __ATOMIC_RELAXED, __HIP_MEMORY_SCOPE_AGENT) < tgt)
        __builtin_amdgcn_s_sleep(1);
    }
    __syncthreads();
    __threadfence();                       // acquire before next step's h stage

    xprow += Hsz;
    Urow  += KH;
  }
}

// ---------------------------------------------------------------------------
// Epilogue: out[m,o] = hs[m,:] @ W_out[:,o] + b_out[o]
// ---------------------------------------------------------------------------
__global__ __launch_bounds__(256) void outproj_kernel(
    const float* __restrict__ hs, const float* __restrict__ W_out,
    const float* __restrict__ b_out, float* __restrict__ out)
{
  const int m = blockIdx.x * 16 + (threadIdx.x >> 4);
  const int o = threadIdx.x & 15;
  if (o >= Osz) return;
  const float* hrow = hs + (size_t)m * Hsz;
  float acc = b_out[o];
#pragma unroll 8
  for (int kk = 0; kk < Hsz; ++kk)
    acc = fmaf(hrow[kk], W_out[(size_t)kk * Osz + o], acc);
  out[(size_t)m * Osz + o] = acc;
}

// ---------------------------------------------------------------------------
extern "C" void kernel_launch(void* const* d_in, const int* in_sizes, int n_in,
                              void* d_out, int out_size, void* d_ws, size_t ws_size,
                              hipStream_t stream) {
  (void)in_sizes; (void)n_in; (void)out_size; (void)ws_size;

  const float* x      = (const float*)d_in[0];
  const float* W_in   = (const float*)d_in[1];
  const float* b_in   = (const float*)d_in[2];
  const float* W_rec  = (const float*)d_in[3];
  const float* bias   = (const float*)d_in[4];
  const float* W_tau1 = (const float*)d_in[5];
  const float* b_tau1 = (const float*)d_in[6];
  const float* W_tau2 = (const float*)d_in[7];
  const float* b_tau2 = (const float*)d_in[8];
  const float* W_out  = (const float*)d_in[9];
  const float* b_out  = (const float*)d_in[10];
  float* out = (float*)d_out;

  char* ws = (char*)d_ws;
  size_t off = 0;
  float* xps = (float*)(ws + off); off += (size_t)Bsz * Tsz * Hsz * 4;  // 128 MiB
  float* U   = (float*)(ws + off); off += (size_t)Bsz * Tsz * KH * 4;   //  64 MiB
  unsigned* P0 = (unsigned*)(ws + off); off += (size_t)256 * Hsz * 4;
  unsigned* P1 = (unsigned*)(ws + off); off += (size_t)256 * KH  * 4;
  unsigned* P2 = (unsigned*)(ws + off); off += (size_t)128 * Hsz * 4;
  float* hstate  = (float*)(ws + off); off += (size_t)Bsz * Hsz * 4;    // 128 KiB
  unsigned* ctrs = (unsigned*)(ws + off); off += (size_t)Bsz * 64 * 4;  //  16 KiB
  float* Astate  = (float*)(ws + off); off += (size_t)Bsz * KH * 4;     //  64 KiB

  const int M = Bsz * Tsz;  // 65536

  // zero h0 + barrier counters (contiguous region)
  hipMemsetAsync(hstate, 0, (size_t)Bsz * Hsz * 4 + (size_t)Bsz * 64 * 4, stream);

  // weight repack
  pack_wrecT_kernel<<<(256 * Hsz + 255) / 256, 256, 0, stream>>>(W_rec, P0);
  pack_rows_kernel<<<(256 * KH + 255) / 256, 256, 0, stream>>>(
      W_tau1 + (size_t)Hsz * KH, P1, 256, KH);
  pack_rows_kernel<<<(128 * Hsz + 255) / 256, 256, 0, stream>>>(W_tau2, P2, 128, Hsz);

  // xp = x @ W_in + b_in
  {
    dim3 grid(M / 64, Hsz / 64);
    gemm_bias_kernel<<<grid, 256, 0, stream>>>(x, W_in, b_in, xps, M, Hsz, Isz);
  }
  // U = xp @ W_tau1[:512] + b_tau1
  {
    dim3 grid(M / 64, KH / 64);
    gemm_bias_kernel<<<grid, 256, 0, stream>>>(xps, W_tau1, b_tau1, U, M, KH, Hsz);
  }
  // scan (256 WGs, 4 per batch element)
  scan_kernel<<<256, 512, 0, stream>>>(xps, U, P0, P1, P2, bias, b_tau2,
                                       hstate, Astate, ctrs);
  // output projection
  outproj_kernel<<<M / 16, 256, 0, stream>>>(xps, W_out, b_out, out);
}

// Round 4
// 8802.690 us; speedup vs baseline: 14.2830x; 14.2830x over previous
//
#include <hip/hip_runtime.h>
#include <hip/hip_fp16.h>
#include <math.h>

#define Bsz 64
#define Tsz 1024
#define Isz 128
#define Hsz 512
#define KH  256   // H/2
#define Osz 10

// ---------------------------------------------------------------------------
// Register-tiled fp32 GEMM: C[M,N] = A[M,K] @ Bw[K,N] + bias[N]
// ---------------------------------------------------------------------------
__global__ __launch_bounds__(256) void gemm_bias_kernel(
    const float* __restrict__ A, const float* __restrict__ Bw,
    const float* __restrict__ bias, float* __restrict__ C,
    int M, int N, int K)
{
  __shared__ float As[32][65];
  const int tid = threadIdx.x;
  const int m0 = blockIdx.x * 64;
  const int n0 = blockIdx.y * 64;
  const int ty = tid >> 4, tx = tid & 15;

  float acc[4][4] = {{0.f}};

  for (int kk = 0; kk < K; kk += 32) {
    __syncthreads();
#pragma unroll
    for (int i = tid; i < 64 * 32; i += 256) {
      int m = i >> 5, k = i & 31;
      As[k][m] = A[(size_t)(m0 + m) * K + kk + k];
    }
    __syncthreads();
#pragma unroll
    for (int k = 0; k < 32; ++k) {
      float a0 = As[k][ty * 4 + 0];
      float a1 = As[k][ty * 4 + 1];
      float a2 = As[k][ty * 4 + 2];
      float a3 = As[k][ty * 4 + 3];
      const float4 bv = *(const float4*)(&Bw[(size_t)(kk + k) * N + n0 + tx * 4]);
      acc[0][0] += a0 * bv.x; acc[0][1] += a0 * bv.y; acc[0][2] += a0 * bv.z; acc[0][3] += a0 * bv.w;
      acc[1][0] += a1 * bv.x; acc[1][1] += a1 * bv.y; acc[1][2] += a1 * bv.z; acc[1][3] += a1 * bv.w;
      acc[2][0] += a2 * bv.x; acc[2][1] += a2 * bv.y; acc[2][2] += a2 * bv.z; acc[2][3] += a2 * bv.w;
      acc[3][0] += a3 * bv.x; acc[3][1] += a3 * bv.y; acc[3][2] += a3 * bv.z; acc[3][3] += a3 * bv.w;
    }
  }

  const float4 bb = *(const float4*)(&bias[n0 + tx * 4]);
#pragma unroll
  for (int i = 0; i < 4; ++i) {
    float4 v;
    v.x = acc[i][0] + bb.x; v.y = acc[i][1] + bb.y;
    v.z = acc[i][2] + bb.z; v.w = acc[i][3] + bb.w;
    *(float4*)(&C[(size_t)(m0 + ty * 4 + i) * N + n0 + tx * 4]) = v;
  }
}

// ---------------------------------------------------------------------------
// f16 helpers + packed dot2
// pack: low 16 = even-index element, high 16 = odd-index element.
// ---------------------------------------------------------------------------
typedef _Float16 hf2_t __attribute__((ext_vector_type(2)));

__device__ __forceinline__ unsigned short f16b(float f) {
  return __half_as_ushort(__float2half_rn(f));
}

__device__ __forceinline__ float dot2(unsigned w, unsigned h, float acc) {
#if __has_builtin(__builtin_amdgcn_fdot2)
  return __builtin_amdgcn_fdot2(__builtin_bit_cast(hf2_t, w),
                                __builtin_bit_cast(hf2_t, h), acc, false);
#else
  float wl = __half2float(__ushort_as_half((unsigned short)(w & 0xffffu)));
  float wh = __half2float(__ushort_as_half((unsigned short)(w >> 16)));
  float hl = __half2float(__ushort_as_half((unsigned short)(h & 0xffffu)));
  float hh_ = __half2float(__ushort_as_half((unsigned short)(h >> 16)));
  return fmaf(wl, hl, fmaf(wh, hh_, acc));
#endif
}

// ---------------------------------------------------------------------------
// Weight repack into chunked-x4 f16-pair layout:
//   element (pair p, col c) of a [P pairs x C cols] pair-matrix is stored at
//   out[(p>>2)*(C*4) + c*4 + (p&3)]   (so each col's pairs are contiguous in
//   groups of 4 -> per-thread uint4 loads, lane-coalesced 16B/lane)
// ---------------------------------------------------------------------------

// P0: W_rec [512][512]: pair p over k, col j = output row of W_rec.
__global__ __launch_bounds__(256) void pack_p0_kernel(
    const float* __restrict__ W_rec, unsigned* __restrict__ P0)
{
  int i = blockIdx.x * 256 + threadIdx.x;           // 256*512 elements
  if (i >= 256 * Hsz) return;
  int p = i >> 9, j = i & 511;
  unsigned lo = f16b(W_rec[(size_t)j * Hsz + 2 * p]);
  unsigned hi = f16b(W_rec[(size_t)j * Hsz + 2 * p + 1]);
  P0[(size_t)(p >> 2) * (Hsz * 4) + j * 4 + (p & 3)] = lo | (hi << 16);
}

// P1: W1b = W_tau1[512:1024] [512][256]: pair p over j (h index), col c.
__global__ __launch_bounds__(256) void pack_p1_kernel(
    const float* __restrict__ W1b, unsigned* __restrict__ P1)
{
  int i = blockIdx.x * 256 + threadIdx.x;           // 256*256 elements
  if (i >= 256 * KH) return;
  int p = i >> 8, c = i & 255;
  unsigned lo = f16b(W1b[(size_t)(2 * p) * KH + c]);
  unsigned hi = f16b(W1b[(size_t)(2 * p + 1) * KH + c]);
  P1[(size_t)(p >> 2) * (KH * 4) + c * 4 + (p & 3)] = lo | (hi << 16);
}

// P2: W_tau2 [256][512]: pair p over k, col j.
__global__ __launch_bounds__(256) void pack_p2_kernel(
    const float* __restrict__ W_tau2, unsigned* __restrict__ P2)
{
  int i = blockIdx.x * 256 + threadIdx.x;           // 128*512 elements
  if (i >= 128 * Hsz) return;
  int p = i >> 9, j = i & 511;
  unsigned lo = f16b(W_tau2[(size_t)(2 * p) * Hsz + j]);
  unsigned hi = f16b(W_tau2[(size_t)(2 * p + 1) * Hsz + j]);
  P2[(size_t)(p >> 2) * (Hsz * 4) + j * 4 + (p & 3)] = lo | (hi << 16);
}

// ---------------------------------------------------------------------------
// Sequential scan. One WG (512 threads) per batch element, no cross-WG sync.
// Thread tid owns column tid (h state in a register). h/A kept as packed f16
// in LDS (each thread stores its own 2 bytes); weights streamed from L2 as
// per-thread-contiguous uint4 (f16 pairs) consumed by v_dot2_f32_f16.
// 3 barriers/step.
// ---------------------------------------------------------------------------
__global__ __launch_bounds__(512) void scan_kernel(
    float* __restrict__ xps,           // in: xp [B,T,H]; out: hs [B,T,H]
    const float* __restrict__ U,       // [B,T,KH] (b_tau1 already added)
    const unsigned* __restrict__ P0,   // chunked [64][512][4]
    const unsigned* __restrict__ P1,   // chunked [64][256][4]
    const unsigned* __restrict__ P2,   // chunked [32][512][4]
    const float* __restrict__ bias,    // [H]
    const float* __restrict__ b_tau2)  // [H]
{
  const int b = blockIdx.x;
  const int tid = threadIdx.x;
  const int hs = tid >> 8;             // tau1 k-half
  const int c  = tid & 255;            // tau1 column

  __shared__ __align__(16) unsigned short hh[2][Hsz];  // packed f16 h, dbuf
  __shared__ __align__(16) unsigned short Ah[KH];      // packed f16 relu(A)
  __shared__ float part[2][KH];

  const float bias_r = bias[tid];
  const float bt2_r  = b_tau2[tid];
  float hold = 0.f;
  hh[0][tid] = 0;                      // f16 +0.0

  float* xprow = xps + (size_t)b * Tsz * Hsz;
  const float* Urow = U + (size_t)b * Tsz * KH;

  const uint4* __restrict__ p0 = (const uint4*)P0 + tid;           // stride 512
  const uint4* __restrict__ p1 = (const uint4*)P1 + hs * 8192 + c; // stride 256
  const uint4* __restrict__ p2 = (const uint4*)P2 + tid;           // stride 512
  const uint4* A4 = (const uint4*)Ah;

  __syncthreads();

  for (int t = 0; t < Tsz; ++t) {
    const uint4* h4 = (const uint4*)hh[t & 1];

    const float xpv = xprow[tid];
    const float Uv = (tid < KH) ? Urow[tid] : 0.f;

    // --- tau1 partial: its 256-element k-half of column c ---
    float pa = 0.f, pb = 0.f;
#pragma unroll 8
    for (int i = 0; i < 32; ++i) {
      const uint4 w = p1[(size_t)i * 256];
      const uint4 hv = h4[hs * 32 + i];
      pa = dot2(w.x, hv.x, pa); pb = dot2(w.y, hv.y, pb);
      pa = dot2(w.z, hv.z, pa); pb = dot2(w.w, hv.w, pb);
    }
    part[hs][c] = pa + pb;
    __syncthreads();                                   // sync1

    if (tid < KH) {
      float a = Uv + part[0][tid] + part[1][tid];
      Ah[tid] = f16b(fmaxf(a, 0.f));
    }
    __syncthreads();                                   // sync2

    // --- tau2: full k=256 for column tid ---
    float s0 = bt2_r, s1 = 0.f;
#pragma unroll 8
    for (int i = 0; i < 32; ++i) {
      const uint4 w = p2[(size_t)i * 512];
      const uint4 av = A4[i];
      s0 = dot2(w.x, av.x, s0); s1 = dot2(w.y, av.y, s1);
      s0 = dot2(w.z, av.z, s0); s1 = dot2(w.w, av.w, s1);
    }

    // --- drive: full k=512 for column tid ---
    float d0 = xpv + bias_r, d1 = 0.f;
#pragma unroll 8
    for (int i = 0; i < 64; ++i) {
      const uint4 w = p0[(size_t)i * 512];
      const uint4 hv = h4[i];
      d0 = dot2(w.x, hv.x, d0); d1 = dot2(w.y, hv.y, d1);
      d0 = dot2(w.z, hv.z, d0); d1 = dot2(w.w, hv.w, d1);
    }

    // --- epilogue: tau, tanh, Euler update ---
    const float tau = 5.0f + 45.0f / (1.0f + __expf(-(s0 + s1)));
    const float e2 = __expf(2.0f * (d0 + d1));
    const float drv = 1.0f - 2.0f / (e2 + 1.0f);       // tanh
    const float hnew = hold + (drv - hold) / tau;
    hold = hnew;
    hh[(t + 1) & 1][tid] = f16b(hnew);
    xprow[tid] = hnew;                                 // hs output (dead xp slot)
    __syncthreads();                                   // sync3

    xprow += Hsz;
    Urow  += KH;
  }
}

// ---------------------------------------------------------------------------
// Epilogue: out[m,o] = hs[m,:] @ W_out[:,o] + b_out[o]
// ---------------------------------------------------------------------------
__global__ __launch_bounds__(256) void outproj_kernel(
    const float* __restrict__ hs, const float* __restrict__ W_out,
    const float* __restrict__ b_out, float* __restrict__ out)
{
  const int m = blockIdx.x * 16 + (threadIdx.x >> 4);
  const int o = threadIdx.x & 15;
  if (o >= Osz) return;
  const float* hrow = hs + (size_t)m * Hsz;
  float acc = b_out[o];
#pragma unroll 8
  for (int kk = 0; kk < Hsz; ++kk)
    acc = fmaf(hrow[kk], W_out[(size_t)kk * Osz + o], acc);
  out[(size_t)m * Osz + o] = acc;
}

// ---------------------------------------------------------------------------
extern "C" void kernel_launch(void* const* d_in, const int* in_sizes, int n_in,
                              void* d_out, int out_size, void* d_ws, size_t ws_size,
                              hipStream_t stream) {
  (void)in_sizes; (void)n_in; (void)out_size; (void)ws_size;

  const float* x      = (const float*)d_in[0];
  const float* W_in   = (const float*)d_in[1];
  const float* b_in   = (const float*)d_in[2];
  const float* W_rec  = (const float*)d_in[3];
  const float* bias   = (const float*)d_in[4];
  const float* W_tau1 = (const float*)d_in[5];
  const float* b_tau1 = (const float*)d_in[6];
  const float* W_tau2 = (const float*)d_in[7];
  const float* b_tau2 = (const float*)d_in[8];
  const float* W_out  = (const float*)d_in[9];
  const float* b_out  = (const float*)d_in[10];
  float* out = (float*)d_out;

  char* ws = (char*)d_ws;
  size_t off = 0;
  float* xps = (float*)(ws + off); off += (size_t)Bsz * Tsz * Hsz * 4;  // 128 MiB
  float* U   = (float*)(ws + off); off += (size_t)Bsz * Tsz * KH * 4;   //  64 MiB
  unsigned* P0 = (unsigned*)(ws + off); off += (size_t)256 * Hsz * 4;   // 512 KiB
  unsigned* P1 = (unsigned*)(ws + off); off += (size_t)256 * KH  * 4;   // 256 KiB
  unsigned* P2 = (unsigned*)(ws + off); off += (size_t)128 * Hsz * 4;   // 256 KiB

  const int M = Bsz * Tsz;  // 65536

  // weight repack (f16 pairs, chunked-x4 layout)
  pack_p0_kernel<<<(256 * Hsz + 255) / 256, 256, 0, stream>>>(W_rec, P0);
  pack_p1_kernel<<<(256 * KH + 255) / 256, 256, 0, stream>>>(
      W_tau1 + (size_t)Hsz * KH, P1);
  pack_p2_kernel<<<(128 * Hsz + 255) / 256, 256, 0, stream>>>(W_tau2, P2);

  // xp = x @ W_in + b_in
  {
    dim3 grid(M / 64, Hsz / 64);
    gemm_bias_kernel<<<grid, 256, 0, stream>>>(x, W_in, b_in, xps, M, Hsz, Isz);
  }
  // U = xp @ W_tau1[:512] + b_tau1
  {
    dim3 grid(M / 64, KH / 64);
    gemm_bias_kernel<<<grid, 256, 0, stream>>>(xps, W_tau1, b_tau1, U, M, KH, Hsz);
  }
  // scan (64 WGs, one per batch element)
  scan_kernel<<<Bsz, 512, 0, stream>>>(xps, U, P0, P1, P2, bias, b_tau2);
  // output projection
  outproj_kernel<<<M / 16, 256, 0, stream>>>(xps, W_out, b_out, out);
}